// Round 10
// baseline (227.870 us; speedup 1.0000x reference)
//
#include <hip/hip_runtime.h>

typedef unsigned short u16;
typedef __attribute__((ext_vector_type(8))) short short8;
typedef __attribute__((ext_vector_type(4))) short short4v;
typedef __attribute__((ext_vector_type(4))) float floatx4;
typedef __attribute__((ext_vector_type(4))) unsigned short ushort4v;

#define B_ 4
#define T_ 2048
#define C_ 1024
#define H_ 16
#define HD_ 64

template <bool V> struct BC { static constexpr bool value = V; };
template <int N> struct ICN { static constexpr int v = N; };

static __device__ __forceinline__ u16 f2bf(float f) {
  union { float f; unsigned int i; } c; c.f = f;
  unsigned int u = c.i;
  return (u16)((u + 0x7FFFu + ((u >> 16) & 1u)) >> 16);
}
// pack 2 fp32 -> bf16x2 (truncation) in one v_perm_b32
static __device__ __forceinline__ unsigned pk2(float lo, float hi) {
  union { float f; unsigned u; } a, b; a.f = hi; b.f = lo;
  return __builtin_amdgcn_perm(a.u, b.u, 0x07060302u);
}
// pack 2 fp32 -> bf16x2 with round-to-nearest
static __device__ __forceinline__ unsigned pk2r(float lo, float hi) {
  return (unsigned)f2bf(lo) | ((unsigned)f2bf(hi) << 16);
}

// async global->LDS DMA, 16 B/lane; LDS dest = wave-uniform base + lane*16
static __device__ __forceinline__ void gload16(const u16* g, u16* l) {
  __builtin_amdgcn_global_load_lds(
      (const __attribute__((address_space(1))) unsigned int*)(g),
      (__attribute__((address_space(3))) unsigned int*)(l), 16, 0, 0);
}

template <int N> static __device__ __forceinline__ void wait_vm_bar() {
  if constexpr (N == 6)
    asm volatile("s_waitcnt vmcnt(6)\n\ts_barrier" ::: "memory");
  else if constexpr (N == 4)
    asm volatile("s_waitcnt vmcnt(4)\n\ts_barrier" ::: "memory");
  else if constexpr (N == 0)
    asm volatile("s_waitcnt vmcnt(0)\n\ts_barrier" ::: "memory");
}

// ---------------- fused prep: convert x + transpose both weights ----------
__global__ __launch_bounds__(256) void prep_k(const float* __restrict__ x,
                                              const float* __restrict__ w_qkv,
                                              const float* __restrict__ w_proj,
                                              u16* __restrict__ xbf,
                                              u16* __restrict__ wqkvT,
                                              u16* __restrict__ wprojT) {
  const int bid = blockIdx.x;
  if (bid < 8192) {
    const int i = bid * 256 + threadIdx.x;
    const float4 f = ((const float4*)x)[i];
    ushort4v o;
    o.x = f2bf(f.x); o.y = f2bf(f.y); o.z = f2bf(f.z); o.w = f2bf(f.w);
    *(ushort4v*)(xbf + (size_t)i * 4) = o;
    return;
  }
  __shared__ u16 tile[32][33];
  const float* in;
  u16* out;
  int R, Cc, tb;
  if (bid < 11264) {
    in = w_qkv; out = wqkvT; R = C_; Cc = 3 * C_; tb = bid - 8192;
  } else {
    in = w_proj; out = wprojT; R = C_; Cc = C_; tb = bid - 11264;
  }
  const int tpr = Cc / 32;
  const int bx = (tb % tpr) * 32;
  const int by = (tb / tpr) * 32;
  const int tx = threadIdx.x & 31;
  const int ty = threadIdx.x >> 5;
  #pragma unroll
  for (int i = ty; i < 32; i += 8)
    tile[i][tx] = f2bf(in[(size_t)(by + i) * Cc + bx + tx]);
  __syncthreads();
  #pragma unroll
  for (int i = ty; i < 32; i += 8)
    out[(size_t)(bx + i) * R + by + tx] = tile[tx][i];
}

// ---------------- GEMM, B^T operand: 4-wave fat-fragment pipeline ---------
// Tile 128 x (NFR*32), 4 waves (2M x 2N). 3-deep LDS K-tile buffers,
// counted vmcnt(LPW); 2 blocks/CU. K hardcoded 1024.
// MODE 1 (NFR=8): qkv GEMM. Q rows (tN<1024) pre-scaled by 0.125*log2e
// (softmax scale folded — attn uses exp2(S) directly). V tiles (tN>=2048)
// transposed through LDS into Vt with kappa-permuted t-order, kappa(t) =
// (t6,t5,t3,t2,t4,t1,t0). kappa preserves (t1,t0), so the 4 consecutive
// t-values of each acc quad stay contiguous: the permutation is applied
// AT THE WRITE (different constant address, zero extra instructions) and
// the read/store side is a plain b128 + contiguous 16B store (round-7
// cost). attn's PV A-fragment then reads a single b128 per (h2,dt).
// MODE 2 (NFR=4): fp32 out + bias, nontemporal.
template <int MODE, int NFR>
__global__ __launch_bounds__(256, 2) void gemm4w(const u16* __restrict__ A,
                                                 const u16* __restrict__ Bt,
                                                 u16* __restrict__ outb,
                                                 u16* __restrict__ outv,
                                                 float* __restrict__ outf,
                                                 const float* __restrict__ bias,
                                                 int M, int N) {
  constexpr int TN = NFR * 32;                 // 256 or 128
  constexpr int BUFA = 4096;                   // u16: 128 rows x 32 k
  constexpr int BUFB = TN * 32;                // u16
  constexpr int BUF = BUFA + BUFB;             // u16 per K-tile buffer
  constexpr int LPW = (8 + TN / 16) / 4;       // gload16 per wave: 6 or 4
  __shared__ __align__(16) u16 lds[3 * BUF];

  const int bid = blockIdx.x;
  const int xcd = bid & 7;
  const int loc = bid >> 3;
  const int tM = (xcd * 8 + (loc & 7)) * 128;  // 64 M-tiles = 8 XCD x 8
  const int tN = (loc >> 3) * TN;
  const int tid = threadIdx.x;
  const int wave = tid >> 6;
  const int lane = tid & 63;
  const int lr = lane & 15;
  const int quad = lane >> 4;
  const int wm = wave >> 1;       // 0..1: 64-row half
  const int wn = wave & 1;        // 0..1: TN/2-col half
  const int csw = (lr >> 1) & 3;
  const int srow = lane >> 2;
  const int skofs = ((lane & 3) ^ ((lane >> 3) & 3)) * 8;

  // per-wave staging descriptors (t-independent)
  const u16* gbase[LPW];
  int ldst[LPW];
  #pragma unroll
  for (int j = 0; j < LPW; j++) {
    const int s = wave * LPW + j;
    if (s < 8) {
      gbase[j] = A + (size_t)(tM + s * 16 + srow) * 1024 + skofs;
      ldst[j] = s * 512;
    } else {
      gbase[j] = Bt + (size_t)(tN + (s - 8) * 16 + srow) * 1024 + skofs;
      ldst[j] = BUFA + (s - 8) * 512;
    }
  }

  const floatx4 zf = {0.f, 0.f, 0.f, 0.f};
  floatx4 acc[4][NFR];
  #pragma unroll
  for (int i = 0; i < 4; i++)
    #pragma unroll
    for (int j = 0; j < NFR; j++) acc[i][j] = zf;

  auto stage = [&](int t, int buf) {
    #pragma unroll
    for (int j = 0; j < LPW; j++)
      gload16(gbase[j] + t * 32, &lds[buf * BUF + ldst[j]]);
  };

  auto ktile = [&](int t, int buf, auto VM) {
    constexpr int vm = decltype(VM)::v;
    const u16* lA = &lds[buf * BUF];
    const u16* lB = lA + BUFA;
    short8 af[4], bfr[NFR];
    #pragma unroll
    for (int mt = 0; mt < 4; mt++)
      af[mt] = *(const short8*)(&lA[(wm * 64 + mt * 16 + lr) * 32 + ((quad ^ csw) * 8)]);
    #pragma unroll
    for (int nt = 0; nt < NFR; nt++)
      bfr[nt] = *(const short8*)(&lB[(wn * (NFR * 16) + nt * 16 + lr) * 32 + ((quad ^ csw) * 8)]);
    if constexpr (vm > 0) stage(t + 2, (buf + 2) % 3);
    __builtin_amdgcn_s_setprio(1);
    #pragma unroll
    for (int mt = 0; mt < 4; mt++)
      #pragma unroll
      for (int nt = 0; nt < NFR; nt++)
        acc[mt][nt] = __builtin_amdgcn_mfma_f32_16x16x32_bf16(af[mt], bfr[nt],
                                                              acc[mt][nt], 0, 0, 0);
    __builtin_amdgcn_s_setprio(0);
    if constexpr (vm > 0) wait_vm_bar<LPW>();
    else if constexpr (vm == 0) wait_vm_bar<0>();
  };

  // prologue: 2 K-tiles staged; wait K-tile 0 (LPW newer loads stay in flight)
  stage(0, 0); stage(1, 1);
  wait_vm_bar<LPW>();

  for (int tb = 0; tb < 10; ++tb) {
    const int t = tb * 3;
    ktile(t,     0, ICN<LPW>{});
    ktile(t + 1, 1, ICN<LPW>{});
    ktile(t + 2, 2, ICN<LPW>{});
  }
  ktile(30, 0, ICN<0>{});
  ktile(31, 1, ICN<-1>{});

  if constexpr (MODE == 1) {
    if (tN >= 2 * C_) {
      // V tile: transpose 128t x 256(4 heads x 64d) through swizzled LDS.
      // kappa applied at the WRITE: acc quad (t0v..t0v+3) lands at
      // pb..pb+3 where pb = kappa(t0v) = wm*64+(mt>>1)*32+quad*8+(mt&1)*4.
      asm volatile("s_barrier" ::: "memory");  // all frag reads done
      #pragma unroll
      for (int mt = 0; mt < 4; mt++) {
        const int pb = wm * 64 + (mt >> 1) * 32 + quad * 8 + (mt & 1) * 4;
        #pragma unroll
        for (int nt = 0; nt < NFR; nt++) {
          const int vrow = wn * (NFR * 16) + nt * 16 + lr;  // head*64 + d
          u16* p = &lds[vrow * 128 + (((pb >> 3) ^ (vrow & 7)) * 8) + (pb & 7)];
          *(unsigned*)(p)     = pk2r(acc[mt][nt][0], acc[mt][nt][1]);
          *(unsigned*)(p + 2) = pk2r(acc[mt][nt][2], acc[mt][nt][3]);
        }
      }
      asm volatile("s_waitcnt lgkmcnt(0)\n\ts_barrier" ::: "memory");
      const int b = tM >> 11;
      const int t0b = tM & (T_ - 1);
      const int h0 = (tN - 2 * C_) >> 6;
      u16* vb = outv + (size_t)(b * H_ + h0) * HD_ * T_;
      #pragma unroll
      for (int i = 0; i < 16; i++) {
        const int lin = tid + i * 256;      // 256 rows x 16 chunks
        const int row = lin >> 4;           // head*64 + d
        const int cp = lin & 15;            // kappa-chunk (already permuted)
        const short8 v = *(const short8*)(&lds[row * 128 + ((cp ^ (row & 7)) * 8)]);
        *(short8*)(vb + (size_t)row * T_ + t0b + cp * 8) = v;
      }
      return;
    }
    // natural epilogue (Q,K): D[row=quad*4+r][col=lr]; Q pre-scaled
    const float qs = (tN < C_) ? 0.18033688f : 1.0f;  // 0.125*log2(e)
    #pragma unroll
    for (int mt = 0; mt < 4; mt++) {
      const int m0 = tM + wm * 64 + mt * 16 + quad * 4;
      #pragma unroll
      for (int nt = 0; nt < NFR; nt++) {
        const int n = tN + wn * (NFR * 16) + nt * 16 + lr;
        #pragma unroll
        for (int r = 0; r < 4; r++)
          outb[(size_t)(m0 + r) * N + n] = f2bf(acc[mt][nt][r] * qs);
      }
    }
  } else {
    #pragma unroll
    for (int mt = 0; mt < 4; mt++) {
      const int m0 = tM + wm * 64 + mt * 16 + quad * 4;
      #pragma unroll
      for (int nt = 0; nt < NFR; nt++) {
        const int n = tN + wn * (NFR * 16) + nt * 16 + lr;
        const float bv = bias[n];
        #pragma unroll
        for (int r = 0; r < 4; r++)
          __builtin_nontemporal_store(acc[mt][nt][r] + bv,
                                      &outf[(size_t)(m0 + r) * N + n]);
      }
    }
  }
}

// ---------------- causal flash attention: S^T/O^T form, register-P --------
// grid 1024 (XCD-swizzled), double-buffered K/V staging.
// Q arrives pre-scaled by 0.125*log2e -> pe = exp2(st) directly.
// Vt is kappa-permuted by the producer -> PV A-fragment is a SINGLE
// ds_read_b128 per (h2,dt).
__global__ __launch_bounds__(256, 4) void attn_k(const u16* __restrict__ qkv,
                                                 const u16* __restrict__ vt,
                                                 u16* __restrict__ y) {
  __shared__ __align__(16) u16 Ks[2 * 4096];    // [buf][kpos][d], chunk-swizzled
  __shared__ __align__(16) u16 Vs[2 * 4096];    // [buf] Vt: [d][kappa(k)], chunk-swizzled
  const int bid = blockIdx.x;
  const int s = bid >> 3;
  const int qp = s >> 3;                     // 0..15
  const int bh = ((s & 7) << 3) | (bid & 7); // all qp of this bh share XCD
  const int b = bh >> 4, h = bh & 15;
  const int tid = threadIdx.x;
  const int wave = tid >> 6;
  const int lane = tid & 63;
  const int lr = lane & 15;
  const int quad = lane >> 4;
  const int qtA = qp, qtB = 31 - qp;         // qtA < qtB always

  const int srow = lane >> 3;
  const int skofs = ((lane & 7) ^ ((lane >> 3) & 7)) * 8;
  const int gsw = lr & 7;

  const size_t RS = 3 * C_;
  const u16* qcol = qkv + (size_t)b * T_ * RS + h * HD_;
  const u16* kcol = qcol + C_;

  const size_t qrA = (size_t)(qtA * 64 + wave * 16 + lr) * RS;
  const size_t qrB = (size_t)(qtB * 64 + wave * 16 + lr) * RS;
  const short8 aq0A = *(const short8*)(qcol + qrA + quad * 8);
  const short8 aq1A = *(const short8*)(qcol + qrA + 32 + quad * 8);
  const short8 aq0B = *(const short8*)(qcol + qrB + quad * 8);
  const short8 aq1B = *(const short8*)(qcol + qrB + 32 + quad * 8);

  const floatx4 zf = {0.f, 0.f, 0.f, 0.f};
  const short8 vones = {16256, 16256, 16256, 16256, 16256, 16256, 16256, 16256};

  floatx4 accA[4], accB[4];  // O^T: lane holds O^T[d=dt*16+quad*4+r][q=lr]
  floatx4 accSA = zf, accSB = zf;  // row sums via ones-MFMA
  #pragma unroll
  for (int i = 0; i < 4; i++) { accA[i] = zf; accB[i] = zf; }

  auto stage = [&](int kt, int buf) {
    #pragma unroll
    for (int j = 0; j < 2; j++) {
      const int seg = wave * 2 + j;
      const int row = seg * 8 + srow;
      gload16(kcol + (size_t)(kt * 64 + row) * RS + skofs, &Ks[buf * 4096 + seg * 512]);
      gload16(vt + ((size_t)bh * HD_ + row) * T_ + kt * 64 + skofs, &Vs[buf * 4096 + seg * 512]);
    }
    __builtin_amdgcn_sched_barrier(0);
  };

  auto core = [&](int cur, auto WA, auto DA, auto DB) {
    constexpr bool wA = decltype(WA)::value;
    constexpr bool dA = decltype(DA)::value;
    constexpr bool dB = decltype(DB)::value;
    const u16* Kb = &Ks[cur * 4096];
    const u16* Vb = &Vs[cur * 4096];
    float peA[4][4], peB[4][4];
    #pragma unroll
    for (int nt = 0; nt < 4; nt++) {
      const short8 bk0 =
          *(const short8*)(&Kb[(nt * 16 + lr) * 64 + ((quad ^ gsw) * 8)]);
      const short8 bk1 =
          *(const short8*)(&Kb[(nt * 16 + lr) * 64 + (((quad + 4) ^ gsw) * 8)]);
      {
        floatx4 st = __builtin_amdgcn_mfma_f32_16x16x32_bf16(
            bk1, aq1B,
            __builtin_amdgcn_mfma_f32_16x16x32_bf16(bk0, aq0B, zf, 0, 0, 0),
            0, 0, 0);
        #pragma unroll
        for (int r = 0; r < 4; r++) {
          float pe = __builtin_amdgcn_exp2f(st[r]);
          if constexpr (dB)
            if (nt * 16 + quad * 4 + r > wave * 16 + lr) pe = 0.f;
          peB[nt][r] = pe;
        }
      }
      if constexpr (wA) {
        floatx4 st = __builtin_amdgcn_mfma_f32_16x16x32_bf16(
            bk1, aq1A,
            __builtin_amdgcn_mfma_f32_16x16x32_bf16(bk0, aq0A, zf, 0, 0, 0),
            0, 0, 0);
        #pragma unroll
        for (int r = 0; r < 4; r++) {
          float pe = __builtin_amdgcn_exp2f(st[r]);
          if constexpr (dA)
            if (nt * 16 + quad * 4 + r > wave * 16 + lr) pe = 0.f;
          peA[nt][r] = pe;
        }
      }
    }

    short8 pB[2], pA[2];
    #pragma unroll
    for (int h2 = 0; h2 < 2; h2++) {
      union { unsigned u[4]; short8 s8; } w;
      w.u[0] = pk2(peB[2 * h2][0], peB[2 * h2][1]);
      w.u[1] = pk2(peB[2 * h2][2], peB[2 * h2][3]);
      w.u[2] = pk2(peB[2 * h2 + 1][0], peB[2 * h2 + 1][1]);
      w.u[3] = pk2(peB[2 * h2 + 1][2], peB[2 * h2 + 1][3]);
      pB[h2] = w.s8;
    }
    if constexpr (wA) {
      #pragma unroll
      for (int h2 = 0; h2 < 2; h2++) {
        union { unsigned u[4]; short8 s8; } w;
        w.u[0] = pk2(peA[2 * h2][0], peA[2 * h2][1]);
        w.u[1] = pk2(peA[2 * h2][2], peA[2 * h2][3]);
        w.u[2] = pk2(peA[2 * h2 + 1][0], peA[2 * h2 + 1][1]);
        w.u[3] = pk2(peA[2 * h2 + 1][2], peA[2 * h2 + 1][3]);
        pA[h2] = w.s8;
      }
    }

    #pragma unroll
    for (int h2 = 0; h2 < 2; h2++) {
      accSB = __builtin_amdgcn_mfma_f32_16x16x32_bf16(vones, pB[h2], accSB, 0, 0, 0);
      if constexpr (wA)
        accSA = __builtin_amdgcn_mfma_f32_16x16x32_bf16(vones, pA[h2], accSA, 0, 0, 0);
      #pragma unroll
      for (int dt = 0; dt < 4; dt++) {
        const short8 av = *(const short8*)(
            &Vb[(dt * 16 + lr) * 64 + (((h2 * 4 + quad) ^ gsw) * 8)]);
        accB[dt] = __builtin_amdgcn_mfma_f32_16x16x32_bf16(av, pB[h2], accB[dt], 0, 0, 0);
        if constexpr (wA)
          accA[dt] = __builtin_amdgcn_mfma_f32_16x16x32_bf16(av, pA[h2], accA[dt], 0, 0, 0);
      }
    }
  };

  stage(0, 0);
  asm volatile("s_waitcnt vmcnt(0)\n\ts_barrier" ::: "memory");
  int cur = 0;
  for (int kt = 0; kt < qtA; kt++) {
    stage(kt + 1, cur ^ 1);
    core(cur, BC<true>{}, BC<false>{}, BC<false>{});
    asm volatile("s_waitcnt vmcnt(0)\n\ts_barrier" ::: "memory");
    cur ^= 1;
  }
  stage(qtA + 1, cur ^ 1);
  core(cur, BC<true>{}, BC<true>{}, BC<false>{});
  asm volatile("s_waitcnt vmcnt(0)\n\ts_barrier" ::: "memory");
  cur ^= 1;
  for (int kt = qtA + 1; kt < qtB; kt++) {
    stage(kt + 1, cur ^ 1);
    core(cur, BC<false>{}, BC<false>{}, BC<false>{});
    asm volatile("s_waitcnt vmcnt(0)\n\ts_barrier" ::: "memory");
    cur ^= 1;
  }
  core(cur, BC<false>{}, BC<false>{}, BC<true>{});

  // epilogue: every lane already holds the full row-sum in accS*[0]
  #pragma unroll
  for (int ph = 0; ph < 2; ph++) {
    const int qt = ph ? qtB : qtA;
    const floatx4* acc = ph ? accB : accA;
    const float inv = 1.f / (ph ? accSB[0] : accSA[0]);
    const int qg = qt * 64 + wave * 16 + lr;
    u16* yrow = y + ((size_t)(b * T_ + qg)) * C_ + h * HD_;
    #pragma unroll
    for (int dt = 0; dt < 4; dt++) {
      ushort4v o;
      #pragma unroll
      for (int r = 0; r < 4; r++) o[r] = f2bf(acc[dt][r] * inv);
      *(ushort4v*)(yrow + dt * 16 + quad * 4) = o;
    }
  }
}

extern "C" void kernel_launch(void* const* d_in, const int* in_sizes, int n_in,
                              void* d_out, int out_size, void* d_ws, size_t ws_size,
                              hipStream_t stream) {
  const float* x      = (const float*)d_in[0];  // [B,T,C] fp32
  const float* w_qkv  = (const float*)d_in[1];  // [C,3C]  fp32
  const float* w_proj = (const float*)d_in[2];  // [C,C]   fp32
  const float* b_proj = (const float*)d_in[3];  // [C]     fp32
  float* out = (float*)d_out;                   // [B,T,C] fp32

  u16* ws = (u16*)d_ws;
  const size_t SZ = (size_t)B_ * T_ * C_;          // 8388608
  u16* xbf    = ws;                                // [B,T,C] bf16 (yw aliases later)
  u16* wqkvT  = xbf + SZ;                          // [3C][C]
  u16* wprojT = wqkvT + (size_t)3 * C_ * C_;       // [C][C]
  u16* qkvw   = wprojT + (size_t)C_ * C_;          // [B,T,3C] natural bf16 (V third unused)
  u16* vtw    = qkvw + 3 * SZ;                     // [B,H,HD,T] kappa-permuted
  u16* yw     = xbf;                               // x dead after gemm1

  prep_k<<<12288, 256, 0, stream>>>(x, w_qkv, w_proj, xbf, wqkvT, wprojT);
  gemm4w<1, 8><<<768, 256, 0, stream>>>(
      xbf, wqkvT, qkvw, vtw, nullptr, nullptr, B_ * T_, 3 * C_);
  attn_k<<<1024, 256, 0, stream>>>(qkvw, vtw, yw);
  gemm4w<2, 4><<<512, 256, 0, stream>>>(
      yw, wprojT, nullptr, nullptr, out, b_proj, B_ * T_, C_);
}

// Round 11
// 221.887 us; speedup vs baseline: 1.0270x; 1.0270x over previous
//
#include <hip/hip_runtime.h>

typedef unsigned short u16;
typedef __attribute__((ext_vector_type(8))) short short8;
typedef __attribute__((ext_vector_type(4))) short short4v;
typedef __attribute__((ext_vector_type(4))) float floatx4;
typedef __attribute__((ext_vector_type(4))) unsigned short ushort4v;

#define B_ 4
#define T_ 2048
#define C_ 1024
#define H_ 16
#define HD_ 64

template <bool V> struct BC { static constexpr bool value = V; };
template <int N> struct ICN { static constexpr int v = N; };

static __device__ __forceinline__ u16 f2bf(float f) {
  union { float f; unsigned int i; } c; c.f = f;
  unsigned int u = c.i;
  return (u16)((u + 0x7FFFu + ((u >> 16) & 1u)) >> 16);
}
// pack 2 fp32 -> bf16x2 (truncation) in one v_perm_b32
static __device__ __forceinline__ unsigned pk2(float lo, float hi) {
  union { float f; unsigned u; } a, b; a.f = hi; b.f = lo;
  return __builtin_amdgcn_perm(a.u, b.u, 0x07060302u);
}
// pack 2 fp32 -> bf16x2 with round-to-nearest
static __device__ __forceinline__ unsigned pk2r(float lo, float hi) {
  return (unsigned)f2bf(lo) | ((unsigned)f2bf(hi) << 16);
}

// async global->LDS DMA, 16 B/lane; LDS dest = wave-uniform base + lane*16
static __device__ __forceinline__ void gload16(const u16* g, u16* l) {
  __builtin_amdgcn_global_load_lds(
      (const __attribute__((address_space(1))) unsigned int*)(g),
      (__attribute__((address_space(3))) unsigned int*)(l), 16, 0, 0);
}

template <int N> static __device__ __forceinline__ void wait_vm_bar() {
  if constexpr (N == 6)
    asm volatile("s_waitcnt vmcnt(6)\n\ts_barrier" ::: "memory");
  else if constexpr (N == 4)
    asm volatile("s_waitcnt vmcnt(4)\n\ts_barrier" ::: "memory");
  else if constexpr (N == 0)
    asm volatile("s_waitcnt vmcnt(0)\n\ts_barrier" ::: "memory");
}

// ---------------- fused prep: convert x + transpose both weights ----------
__global__ __launch_bounds__(256) void prep_k(const float* __restrict__ x,
                                              const float* __restrict__ w_qkv,
                                              const float* __restrict__ w_proj,
                                              u16* __restrict__ xbf,
                                              u16* __restrict__ wqkvT,
                                              u16* __restrict__ wprojT) {
  const int bid = blockIdx.x;
  if (bid < 8192) {
    const int i = bid * 256 + threadIdx.x;
    const float4 f = ((const float4*)x)[i];
    ushort4v o;
    o.x = f2bf(f.x); o.y = f2bf(f.y); o.z = f2bf(f.z); o.w = f2bf(f.w);
    *(ushort4v*)(xbf + (size_t)i * 4) = o;
    return;
  }
  __shared__ u16 tile[32][33];
  const float* in;
  u16* out;
  int R, Cc, tb;
  if (bid < 11264) {
    in = w_qkv; out = wqkvT; R = C_; Cc = 3 * C_; tb = bid - 8192;
  } else {
    in = w_proj; out = wprojT; R = C_; Cc = C_; tb = bid - 11264;
  }
  const int tpr = Cc / 32;
  const int bx = (tb % tpr) * 32;
  const int by = (tb / tpr) * 32;
  const int tx = threadIdx.x & 31;
  const int ty = threadIdx.x >> 5;
  #pragma unroll
  for (int i = ty; i < 32; i += 8)
    tile[i][tx] = f2bf(in[(size_t)(by + i) * Cc + bx + tx]);
  __syncthreads();
  #pragma unroll
  for (int i = ty; i < 32; i += 8)
    out[(size_t)(bx + i) * R + by + tx] = tile[tx][i];
}

// ---------------- GEMM, B^T operand: 4-wave fat-fragment pipeline ---------
// Tile 128 x (NFR*32), 4 waves (2M x 2N). 3-deep LDS K-tile buffers,
// counted vmcnt(LPW); 2 blocks/CU. K hardcoded 1024.
// MODE 1 (NFR=8): qkv GEMM. Q rows (tN<1024) pre-scaled by 0.125*log2e
// (softmax scale folded — attn uses exp2(S) directly). V tiles (tN>=2048)
// transposed through LDS into Vt with kappa-permuted t-order, kappa(t) =
// (t6,t5,t3,t2,t4,t1,t0). kappa preserves (t1,t0), so the 4 consecutive
// t-values of each acc quad stay contiguous: the permutation is applied
// AT THE WRITE (different constant address, zero extra instructions; the
// two bf16x2 words are merged into ONE aligned 8B ds_write) and the
// read/store side is a plain b128 + contiguous 16B store. attn's PV
// A-fragment then reads a single b128 per (h2,dt).
// MODE 2 (NFR=4): fp32 out + bias, nontemporal.
template <int MODE, int NFR>
__global__ __launch_bounds__(256, 2) void gemm4w(const u16* __restrict__ A,
                                                 const u16* __restrict__ Bt,
                                                 u16* __restrict__ outb,
                                                 u16* __restrict__ outv,
                                                 float* __restrict__ outf,
                                                 const float* __restrict__ bias,
                                                 int M, int N) {
  constexpr int TN = NFR * 32;                 // 256 or 128
  constexpr int BUFA = 4096;                   // u16: 128 rows x 32 k
  constexpr int BUFB = TN * 32;                // u16
  constexpr int BUF = BUFA + BUFB;             // u16 per K-tile buffer
  constexpr int LPW = (8 + TN / 16) / 4;       // gload16 per wave: 6 or 4
  __shared__ __align__(16) u16 lds[3 * BUF];

  const int bid = blockIdx.x;
  const int xcd = bid & 7;
  const int loc = bid >> 3;
  const int tM = (xcd * 8 + (loc & 7)) * 128;  // 64 M-tiles = 8 XCD x 8
  const int tN = (loc >> 3) * TN;
  const int tid = threadIdx.x;
  const int wave = tid >> 6;
  const int lane = tid & 63;
  const int lr = lane & 15;
  const int quad = lane >> 4;
  const int wm = wave >> 1;       // 0..1: 64-row half
  const int wn = wave & 1;        // 0..1: TN/2-col half
  const int csw = (lr >> 1) & 3;
  const int srow = lane >> 2;
  const int skofs = ((lane & 3) ^ ((lane >> 3) & 3)) * 8;

  // per-wave staging descriptors (t-independent)
  const u16* gbase[LPW];
  int ldst[LPW];
  #pragma unroll
  for (int j = 0; j < LPW; j++) {
    const int s = wave * LPW + j;
    if (s < 8) {
      gbase[j] = A + (size_t)(tM + s * 16 + srow) * 1024 + skofs;
      ldst[j] = s * 512;
    } else {
      gbase[j] = Bt + (size_t)(tN + (s - 8) * 16 + srow) * 1024 + skofs;
      ldst[j] = BUFA + (s - 8) * 512;
    }
  }

  const floatx4 zf = {0.f, 0.f, 0.f, 0.f};
  floatx4 acc[4][NFR];
  #pragma unroll
  for (int i = 0; i < 4; i++)
    #pragma unroll
    for (int j = 0; j < NFR; j++) acc[i][j] = zf;

  auto stage = [&](int t, int buf) {
    #pragma unroll
    for (int j = 0; j < LPW; j++)
      gload16(gbase[j] + t * 32, &lds[buf * BUF + ldst[j]]);
  };

  auto ktile = [&](int t, int buf, auto VM) {
    constexpr int vm = decltype(VM)::v;
    const u16* lA = &lds[buf * BUF];
    const u16* lB = lA + BUFA;
    short8 af[4], bfr[NFR];
    #pragma unroll
    for (int mt = 0; mt < 4; mt++)
      af[mt] = *(const short8*)(&lA[(wm * 64 + mt * 16 + lr) * 32 + ((quad ^ csw) * 8)]);
    #pragma unroll
    for (int nt = 0; nt < NFR; nt++)
      bfr[nt] = *(const short8*)(&lB[(wn * (NFR * 16) + nt * 16 + lr) * 32 + ((quad ^ csw) * 8)]);
    if constexpr (vm > 0) stage(t + 2, (buf + 2) % 3);
    __builtin_amdgcn_s_setprio(1);
    #pragma unroll
    for (int mt = 0; mt < 4; mt++)
      #pragma unroll
      for (int nt = 0; nt < NFR; nt++)
        acc[mt][nt] = __builtin_amdgcn_mfma_f32_16x16x32_bf16(af[mt], bfr[nt],
                                                              acc[mt][nt], 0, 0, 0);
    __builtin_amdgcn_s_setprio(0);
    if constexpr (vm > 0) wait_vm_bar<LPW>();
    else if constexpr (vm == 0) wait_vm_bar<0>();
  };

  // prologue: 2 K-tiles staged; wait K-tile 0 (LPW newer loads stay in flight)
  stage(0, 0); stage(1, 1);
  wait_vm_bar<LPW>();

  for (int tb = 0; tb < 10; ++tb) {
    const int t = tb * 3;
    ktile(t,     0, ICN<LPW>{});
    ktile(t + 1, 1, ICN<LPW>{});
    ktile(t + 2, 2, ICN<LPW>{});
  }
  ktile(30, 0, ICN<0>{});
  ktile(31, 1, ICN<-1>{});

  if constexpr (MODE == 1) {
    if (tN >= 2 * C_) {
      // V tile: transpose 128t x 256(4 heads x 64d) through swizzled LDS.
      // kappa applied at the WRITE: acc quad (t0v..t0v+3) lands at
      // pb..pb+3 where pb = kappa(t0v) = wm*64+(mt>>1)*32+quad*8+(mt&1)*4.
      // pb&7 in {0,4} -> the quad is one aligned 8B slot: single ds_write.
      asm volatile("s_barrier" ::: "memory");  // all frag reads done
      #pragma unroll
      for (int mt = 0; mt < 4; mt++) {
        const int pb = wm * 64 + (mt >> 1) * 32 + quad * 8 + (mt & 1) * 4;
        #pragma unroll
        for (int nt = 0; nt < NFR; nt++) {
          const int vrow = wn * (NFR * 16) + nt * 16 + lr;  // head*64 + d
          u16* p = &lds[vrow * 128 + (((pb >> 3) ^ (vrow & 7)) * 8) + (pb & 7)];
          *(uint2*)(p) = make_uint2(pk2r(acc[mt][nt][0], acc[mt][nt][1]),
                                    pk2r(acc[mt][nt][2], acc[mt][nt][3]));
        }
      }
      asm volatile("s_waitcnt lgkmcnt(0)\n\ts_barrier" ::: "memory");
      const int b = tM >> 11;
      const int t0b = tM & (T_ - 1);
      const int h0 = (tN - 2 * C_) >> 6;
      u16* vb = outv + (size_t)(b * H_ + h0) * HD_ * T_;
      #pragma unroll
      for (int i = 0; i < 16; i++) {
        const int lin = tid + i * 256;      // 256 rows x 16 chunks
        const int row = lin >> 4;           // head*64 + d
        const int cp = lin & 15;            // kappa-chunk (already permuted)
        const short8 v = *(const short8*)(&lds[row * 128 + ((cp ^ (row & 7)) * 8)]);
        *(short8*)(vb + (size_t)row * T_ + t0b + cp * 8) = v;
      }
      return;
    }
    // natural epilogue (Q,K): D[row=quad*4+r][col=lr]; Q pre-scaled
    const float qs = (tN < C_) ? 0.18033688f : 1.0f;  // 0.125*log2(e)
    #pragma unroll
    for (int mt = 0; mt < 4; mt++) {
      const int m0 = tM + wm * 64 + mt * 16 + quad * 4;
      #pragma unroll
      for (int nt = 0; nt < NFR; nt++) {
        const int n = tN + wn * (NFR * 16) + nt * 16 + lr;
        #pragma unroll
        for (int r = 0; r < 4; r++)
          outb[(size_t)(m0 + r) * N + n] = f2bf(acc[mt][nt][r] * qs);
      }
    }
  } else {
    #pragma unroll
    for (int mt = 0; mt < 4; mt++) {
      const int m0 = tM + wm * 64 + mt * 16 + quad * 4;
      #pragma unroll
      for (int nt = 0; nt < NFR; nt++) {
        const int n = tN + wn * (NFR * 16) + nt * 16 + lr;
        const float bv = bias[n];
        #pragma unroll
        for (int r = 0; r < 4; r++)
          __builtin_nontemporal_store(acc[mt][nt][r] + bv,
                                      &outf[(size_t)(m0 + r) * N + n]);
      }
    }
  }
}

// ---------------- causal flash attention: S^T/O^T form, register-P --------
// grid 1024 (XCD-swizzled), double-buffered K/V staging.
// Q arrives pre-scaled by 0.125*log2e -> pe = exp2(st) directly.
// Vt is kappa-permuted by the producer -> PV A-fragment is a SINGLE
// ds_read_b128 per (h2,dt).
__global__ __launch_bounds__(256, 4) void attn_k(const u16* __restrict__ qkv,
                                                 const u16* __restrict__ vt,
                                                 u16* __restrict__ y) {
  __shared__ __align__(16) u16 Ks[2 * 4096];    // [buf][kpos][d], chunk-swizzled
  __shared__ __align__(16) u16 Vs[2 * 4096];    // [buf] Vt: [d][kappa(k)], chunk-swizzled
  const int bid = blockIdx.x;
  const int s = bid >> 3;
  const int qp = s >> 3;                     // 0..15
  const int bh = ((s & 7) << 3) | (bid & 7); // all qp of this bh share XCD
  const int b = bh >> 4, h = bh & 15;
  const int tid = threadIdx.x;
  const int wave = tid >> 6;
  const int lane = tid & 63;
  const int lr = lane & 15;
  const int quad = lane >> 4;
  const int qtA = qp, qtB = 31 - qp;         // qtA < qtB always

  const int srow = lane >> 3;
  const int skofs = ((lane & 7) ^ ((lane >> 3) & 7)) * 8;
  const int gsw = lr & 7;

  const size_t RS = 3 * C_;
  const u16* qcol = qkv + (size_t)b * T_ * RS + h * HD_;
  const u16* kcol = qcol + C_;

  const size_t qrA = (size_t)(qtA * 64 + wave * 16 + lr) * RS;
  const size_t qrB = (size_t)(qtB * 64 + wave * 16 + lr) * RS;
  const short8 aq0A = *(const short8*)(qcol + qrA + quad * 8);
  const short8 aq1A = *(const short8*)(qcol + qrA + 32 + quad * 8);
  const short8 aq0B = *(const short8*)(qcol + qrB + quad * 8);
  const short8 aq1B = *(const short8*)(qcol + qrB + 32 + quad * 8);

  const floatx4 zf = {0.f, 0.f, 0.f, 0.f};
  const short8 vones = {16256, 16256, 16256, 16256, 16256, 16256, 16256, 16256};

  floatx4 accA[4], accB[4];  // O^T: lane holds O^T[d=dt*16+quad*4+r][q=lr]
  floatx4 accSA = zf, accSB = zf;  // row sums via ones-MFMA
  #pragma unroll
  for (int i = 0; i < 4; i++) { accA[i] = zf; accB[i] = zf; }

  auto stage = [&](int kt, int buf) {
    #pragma unroll
    for (int j = 0; j < 2; j++) {
      const int seg = wave * 2 + j;
      const int row = seg * 8 + srow;
      gload16(kcol + (size_t)(kt * 64 + row) * RS + skofs, &Ks[buf * 4096 + seg * 512]);
      gload16(vt + ((size_t)bh * HD_ + row) * T_ + kt * 64 + skofs, &Vs[buf * 4096 + seg * 512]);
    }
    __builtin_amdgcn_sched_barrier(0);
  };

  auto core = [&](int cur, auto WA, auto DA, auto DB) {
    constexpr bool wA = decltype(WA)::value;
    constexpr bool dA = decltype(DA)::value;
    constexpr bool dB = decltype(DB)::value;
    const u16* Kb = &Ks[cur * 4096];
    const u16* Vb = &Vs[cur * 4096];
    float peA[4][4], peB[4][4];
    #pragma unroll
    for (int nt = 0; nt < 4; nt++) {
      const short8 bk0 =
          *(const short8*)(&Kb[(nt * 16 + lr) * 64 + ((quad ^ gsw) * 8)]);
      const short8 bk1 =
          *(const short8*)(&Kb[(nt * 16 + lr) * 64 + (((quad + 4) ^ gsw) * 8)]);
      {
        floatx4 st = __builtin_amdgcn_mfma_f32_16x16x32_bf16(
            bk1, aq1B,
            __builtin_amdgcn_mfma_f32_16x16x32_bf16(bk0, aq0B, zf, 0, 0, 0),
            0, 0, 0);
        #pragma unroll
        for (int r = 0; r < 4; r++) {
          float pe = __builtin_amdgcn_exp2f(st[r]);
          if constexpr (dB)
            if (nt * 16 + quad * 4 + r > wave * 16 + lr) pe = 0.f;
          peB[nt][r] = pe;
        }
      }
      if constexpr (wA) {
        floatx4 st = __builtin_amdgcn_mfma_f32_16x16x32_bf16(
            bk1, aq1A,
            __builtin_amdgcn_mfma_f32_16x16x32_bf16(bk0, aq0A, zf, 0, 0, 0),
            0, 0, 0);
        #pragma unroll
        for (int r = 0; r < 4; r++) {
          float pe = __builtin_amdgcn_exp2f(st[r]);
          if constexpr (dA)
            if (nt * 16 + quad * 4 + r > wave * 16 + lr) pe = 0.f;
          peA[nt][r] = pe;
        }
      }
    }

    short8 pB[2], pA[2];
    #pragma unroll
    for (int h2 = 0; h2 < 2; h2++) {
      union { unsigned u[4]; short8 s8; } w;
      w.u[0] = pk2(peB[2 * h2][0], peB[2 * h2][1]);
      w.u[1] = pk2(peB[2 * h2][2], peB[2 * h2][3]);
      w.u[2] = pk2(peB[2 * h2 + 1][0], peB[2 * h2 + 1][1]);
      w.u[3] = pk2(peB[2 * h2 + 1][2], peB[2 * h2 + 1][3]);
      pB[h2] = w.s8;
    }
    if constexpr (wA) {
      #pragma unroll
      for (int h2 = 0; h2 < 2; h2++) {
        union { unsigned u[4]; short8 s8; } w;
        w.u[0] = pk2(peA[2 * h2][0], peA[2 * h2][1]);
        w.u[1] = pk2(peA[2 * h2][2], peA[2 * h2][3]);
        w.u[2] = pk2(peA[2 * h2 + 1][0], peA[2 * h2 + 1][1]);
        w.u[3] = pk2(peA[2 * h2 + 1][2], peA[2 * h2 + 1][3]);
        pA[h2] = w.s8;
      }
    }

    #pragma unroll
    for (int h2 = 0; h2 < 2; h2++) {
      accSB = __builtin_amdgcn_mfma_f32_16x16x32_bf16(vones, pB[h2], accSB, 0, 0, 0);
      if constexpr (wA)
        accSA = __builtin_amdgcn_mfma_f32_16x16x32_bf16(vones, pA[h2], accSA, 0, 0, 0);
      #pragma unroll
      for (int dt = 0; dt < 4; dt++) {
        const short8 av = *(const short8*)(
            &Vb[(dt * 16 + lr) * 64 + (((h2 * 4 + quad) ^ gsw) * 8)]);
        accB[dt] = __builtin_amdgcn_mfma_f32_16x16x32_bf16(av, pB[h2], accB[dt], 0, 0, 0);
        if constexpr (wA)
          accA[dt] = __builtin_amdgcn_mfma_f32_16x16x32_bf16(av, pA[h2], accA[dt], 0, 0, 0);
      }
    }
  };

  stage(0, 0);
  asm volatile("s_waitcnt vmcnt(0)\n\ts_barrier" ::: "memory");
  int cur = 0;
  for (int kt = 0; kt < qtA; kt++) {
    stage(kt + 1, cur ^ 1);
    core(cur, BC<true>{}, BC<false>{}, BC<false>{});
    asm volatile("s_waitcnt vmcnt(0)\n\ts_barrier" ::: "memory");
    cur ^= 1;
  }
  stage(qtA + 1, cur ^ 1);
  core(cur, BC<true>{}, BC<true>{}, BC<false>{});
  asm volatile("s_waitcnt vmcnt(0)\n\ts_barrier" ::: "memory");
  cur ^= 1;
  for (int kt = qtA + 1; kt < qtB; kt++) {
    stage(kt + 1, cur ^ 1);
    core(cur, BC<false>{}, BC<false>{}, BC<false>{});
    asm volatile("s_waitcnt vmcnt(0)\n\ts_barrier" ::: "memory");
    cur ^= 1;
  }
  core(cur, BC<false>{}, BC<false>{}, BC<true>{});

  // epilogue: every lane already holds the full row-sum in accS*[0]
  #pragma unroll
  for (int ph = 0; ph < 2; ph++) {
    const int qt = ph ? qtB : qtA;
    const floatx4* acc = ph ? accB : accA;
    const float inv = 1.f / (ph ? accSB[0] : accSA[0]);
    const int qg = qt * 64 + wave * 16 + lr;
    u16* yrow = y + ((size_t)(b * T_ + qg)) * C_ + h * HD_;
    #pragma unroll
    for (int dt = 0; dt < 4; dt++) {
      ushort4v o;
      #pragma unroll
      for (int r = 0; r < 4; r++) o[r] = f2bf(acc[dt][r] * inv);
      *(ushort4v*)(yrow + dt * 16 + quad * 4) = o;
    }
  }
}

extern "C" void kernel_launch(void* const* d_in, const int* in_sizes, int n_in,
                              void* d_out, int out_size, void* d_ws, size_t ws_size,
                              hipStream_t stream) {
  const float* x      = (const float*)d_in[0];  // [B,T,C] fp32
  const float* w_qkv  = (const float*)d_in[1];  // [C,3C]  fp32
  const float* w_proj = (const float*)d_in[2];  // [C,C]   fp32
  const float* b_proj = (const float*)d_in[3];  // [C]     fp32
  float* out = (float*)d_out;                   // [B,T,C] fp32

  u16* ws = (u16*)d_ws;
  const size_t SZ = (size_t)B_ * T_ * C_;          // 8388608
  u16* xbf    = ws;                                // [B,T,C] bf16 (yw aliases later)
  u16* wqkvT  = xbf + SZ;                          // [3C][C]
  u16* wprojT = wqkvT + (size_t)3 * C_ * C_;       // [C][C]
  u16* qkvw   = wprojT + (size_t)C_ * C_;          // [B,T,3C] natural bf16 (V third unused)
  u16* vtw    = qkvw + 3 * SZ;                     // [B,H,HD,T] kappa-permuted
  u16* yw     = xbf;                               // x dead after gemm1

  prep_k<<<12288, 256, 0, stream>>>(x, w_qkv, w_proj, xbf, wqkvT, wprojT);
  gemm4w<1, 8><<<768, 256, 0, stream>>>(
      xbf, wqkvT, qkvw, vtw, nullptr, nullptr, B_ * T_, 3 * C_);
  attn_k<<<1024, 256, 0, stream>>>(qkvw, vtw, yw);
  gemm4w<2, 4><<<512, 256, 0, stream>>>(
      yw, wprojT, nullptr, nullptr, out, b_proj, B_ * T_, C_);
}